// Round 2
// baseline (176.491 us; speedup 1.0000x reference)
//
#include <hip/hip_runtime.h>

constexpr int PIX  = 513 * 513;  // 263169
constexpr int NIN  = 64;
constexpr int NOUT = 64;

// S = over + under, D = over - under
// A_o = sum_i W[o,i]*S[i],  B_o = sum_i |W[o,i]|*D[i]
// out_over  = 0.5*(A+B) + bias ; out_under = 0.5*(A-B) + bias
__global__ __launch_bounds__(256, 4) void combined_bounds_kernel(
    const float* __restrict__ under,
    const float* __restrict__ over,
    const float* __restrict__ W,
    const float* __restrict__ bias,
    float* __restrict__ out_under,
    float* __restrict__ out_over)
{
    __shared__ float Wt[NIN * NOUT];   // transposed: Wt[i*64 + o], 16 KB
    __shared__ float Blds[NOUT];

    // Stage + transpose weights (one-time; staging bank conflicts negligible)
    {
        const int t = threadIdx.x;
        #pragma unroll
        for (int k = 0; k < 16; ++k) {
            const int idx = t + 256 * k;        // idx = o*64 + i
            const int o = idx >> 6, i = idx & 63;
            Wt[i * 64 + o] = W[idx];
        }
        if (t < NOUT) Blds[t] = bias[t];
    }
    __syncthreads();

    const int p = blockIdx.x * 256 + threadIdx.x;
    if (p >= PIX) return;

    const float* overp  = over + p;
    const float* underp = under + p;

    // Two output chunks of 32: 64 accumulators live at a time.
    // Chunk 1 re-reads inputs from L3 (inputs stay resident thanks to NT stores).
    #pragma unroll 1
    for (int c = 0; c < 2; ++c) {
        const int j0 = c * 32;
        float accA[32], accB[32];
        #pragma unroll
        for (int j = 0; j < 32; ++j) { accA[j] = 0.f; accB[j] = 0.f; }

        #pragma unroll 4
        for (int i = 0; i < NIN; ++i) {
            const float ov = overp[(size_t)i * PIX];
            const float uv = underp[(size_t)i * PIX];
            const float S = ov + uv;
            const float D = ov - uv;
            // Wave-uniform broadcast reads of 32 consecutive weights (128B-aligned)
            const float4* wrow = (const float4*)&Wt[i * 64 + j0];
            #pragma unroll
            for (int jj = 0; jj < 8; ++jj) {
                const float4 w4 = wrow[jj];
                accA[jj * 4 + 0] += w4.x * S;  accB[jj * 4 + 0] += fabsf(w4.x) * D;
                accA[jj * 4 + 1] += w4.y * S;  accB[jj * 4 + 1] += fabsf(w4.y) * D;
                accA[jj * 4 + 2] += w4.z * S;  accB[jj * 4 + 2] += fabsf(w4.z) * D;
                accA[jj * 4 + 3] += w4.w * S;  accB[jj * 4 + 3] += fabsf(w4.w) * D;
            }
        }

        #pragma unroll
        for (int j = 0; j < 32; ++j) {
            const int o = j0 + j;
            const float b  = Blds[o];
            const float vo = 0.5f * (accA[j] + accB[j]) + b;
            const float vu = 0.5f * (accA[j] - accB[j]) + b;
            // Nontemporal: don't let output writes evict inputs from L3
            __builtin_nontemporal_store(vo, &out_over[(size_t)o * PIX + p]);
            __builtin_nontemporal_store(vu, &out_under[(size_t)o * PIX + p]);
        }
    }
}

extern "C" void kernel_launch(void* const* d_in, const int* in_sizes, int n_in,
                              void* d_out, int out_size, void* d_ws, size_t ws_size,
                              hipStream_t stream) {
    const float* under = (const float*)d_in[0];
    const float* over  = (const float*)d_in[1];
    const float* W     = (const float*)d_in[2];
    const float* bias  = (const float*)d_in[3];
    float* out_under = (float*)d_out;
    float* out_over  = out_under + (size_t)NOUT * PIX;

    const int blocks = (PIX + 255) / 256;
    combined_bounds_kernel<<<blocks, 256, 0, stream>>>(under, over, W, bias,
                                                       out_under, out_over);
}